// Round 4
// baseline (328.784 us; speedup 1.0000x reference)
//
#include <hip/hip_runtime.h>
#include <math.h>

#define N_INP 128
#define N_HID 512
#define N_OUT 256
#define N_HEADS 64
#define N_SM 4
#define EPS_GN 1e-5f
#define TINY 1e-14f

__device__ __forceinline__ float wave_sum(float v) {
#pragma unroll
  for (int off = 32; off; off >>= 1) v += __shfl_down(v, off);
  return v;
}
__device__ __forceinline__ float wave_max(float v) {
#pragma unroll
  for (int off = 32; off; off >>= 1) v = fmaxf(v, __shfl_down(v, off));
  return v;
}

// Block reductions: ALL threads must call; `red` needs blockDim/64 slots.
__device__ __forceinline__ float block_sum(float v, float* red) {
  int wave = threadIdx.x >> 6, lane = threadIdx.x & 63;
  int nw = blockDim.x >> 6;
  v = wave_sum(v);
  __syncthreads();
  if (lane == 0) red[wave] = v;
  __syncthreads();
  float s = 0.f;
  for (int i = 0; i < nw; ++i) s += red[i];
  return s;
}
__device__ __forceinline__ float block_max(float v, float* red) {
  int wave = threadIdx.x >> 6, lane = threadIdx.x & 63;
  int nw = blockDim.x >> 6;
  v = wave_max(v);
  __syncthreads();
  if (lane == 0) red[wave] = v;
  __syncthreads();
  float s = -3.4e38f;
  for (int i = 0; i < nw; ++i) s = fmaxf(s, red[i]);
  return s;
}

// K1: 256 blocks = (head h, quarter oq). Redundant sub compute (x L2-hot),
// 128 raw z1 rows per block. Also zeroes osm and the per-head counters
// (stream ordering guarantees visibility to K2).
__global__ __launch_bounds__(512) void k_z1(
    const float* __restrict__ x, const float* __restrict__ qw,
    const float* __restrict__ w1, float* __restrict__ z1,
    float* __restrict__ osm, int* __restrict__ cnt) {
  int blk = blockIdx.x;            // h*4 + oq
  int h = blk >> 2, oq = blk & 3;
  int tid = threadIdx.x, wave = tid >> 6, lane = tid & 63;
  __shared__ float sub_s[N_INP];

  if (tid < 64) osm[blk * 64 + tid] = 0.f;   // 256 blocks x 64 = 16384
  if (oq == 0 && tid == 0) cnt[h] = 0;

  // sub[r] = x[r]·qw[h]; 8 waves × 16 rows
  float2 qv = ((const float2*)(qw + h * N_INP))[lane];
  for (int r = wave; r < N_INP; r += 8) {
    float2 xv = ((const float2*)(x + r * N_INP))[lane];
    float p = wave_sum(xv.x * qv.x + xv.y * qv.y);
    if (lane == 0) sub_s[r] = p;
  }
  __syncthreads();

  // z1 rows [oq*128, oq*128+128): 8 waves × 16 rows
  float2 sv = ((const float2*)sub_s)[lane];
  const float* w1h = w1 + ((size_t)h * N_HID + (size_t)oq * 128) * N_INP;
  for (int k = 0; k < 16; ++k) {
    int o = wave * 16 + k;  // 0..127
    float2 wv = ((const float2*)(w1h + (size_t)o * N_INP))[lane];
    float p = wave_sum(wv.x * sv.x + wv.y * sv.y);
    if (lane == 0) z1[h * N_HID + oq * 128 + o] = p;
  }
}

// K2: 256 blocks = one per (s,h). GN1+softplus from z1 (redundant x4 per head,
// deterministic), 512KB w2 stream + GN2 + softmax + atomic accumulate, plus
// this block's 64 ws rows fused in. The 4th finisher of each head computes the
// gate + final outputs (last-block-done pattern; device-scope atomics only).
__global__ __launch_bounds__(1024) void k_main(
    const float* __restrict__ z1, const float* __restrict__ g1,
    const float* __restrict__ b1, const float* __restrict__ w2,
    const float* __restrict__ g2, const float* __restrict__ b2,
    const float* __restrict__ wsc, const float* __restrict__ last,
    const float* __restrict__ woo, float* __restrict__ osm,
    float* __restrict__ scal, int* __restrict__ cnt,
    float* __restrict__ out) {
  int blk = blockIdx.x;            // s*64 + h
  int s = blk >> 6, h = blk & 63;
  int tid = threadIdx.x, wave = tid >> 6, lane = tid & 63;
  __shared__ float h1_s[N_HID];
  __shared__ float z_s[N_OUT];
  __shared__ float red[16];
  __shared__ int bcast;

  // GN1 over 512 + softplus -> h1_s (LDS)
  float v1 = (tid < N_HID) ? z1[h * N_HID + tid] : 0.f;
  float s1 = block_sum(v1, red);
  float ss1 = block_sum(v1 * v1, red);
  float mu1 = s1 * (1.f / N_HID);
  float var1 = ss1 * (1.f / N_HID) - mu1 * mu1;
  float r1 = rsqrtf(var1 + EPS_GN);
  if (tid < N_HID) {
    float zz = (v1 - mu1) * r1 * g1[h * N_HID + tid] + b1[h * N_HID + tid];
    h1_s[tid] = fmaxf(zz, 0.f) + log1pf(expf(-fabsf(zz)));
  }
  __syncthreads();

  // per-lane o-invariant h1 fragment in registers
  float4 ha = ((const float4*)h1_s)[lane];        // i = 4l..4l+3
  float4 hb = ((const float4*)h1_s)[64 + lane];   // i = 256+4l..

  // fused ws slice: rows o in [s*64, (s+1)*64); atomicExch store = coherent
  for (int k = 0; k < 4; ++k) {
    int o = s * 64 + wave * 4 + k;
    float4 v = ((const float4*)(wsc + ((size_t)(h * N_OUT + o)) * N_OUT))[lane];
    float p = wave_sum(v.x + v.y + v.z + v.w);
    if (lane == 0) atomicExch(&scal[o * N_HEADS + h], p);
  }

  // main stream: z[o] = w2[s][h][o]·h1
  const float* w2base = w2 + (size_t)blk * N_OUT * N_HID;
  for (int k = 0; k < 16; ++k) {
    int o = wave * 16 + k;
    const float4* row = (const float4*)(w2base + (size_t)o * N_HID);
    float4 wa = row[lane];
    float4 wb = row[64 + lane];
    float p = wa.x * ha.x + wa.y * ha.y + wa.z * ha.z + wa.w * ha.w +
              wb.x * hb.x + wb.y * hb.y + wb.z * hb.z + wb.w * hb.w;
    p = wave_sum(p);
    if (lane == 0) z_s[o] = p;
  }
  __syncthreads();

  // GN2 over 256 + softmax + atomic accumulate over s
  float v = (tid < N_OUT) ? z_s[tid] : 0.f;
  float sz = block_sum(v, red);
  float ssz = block_sum(v * v, red);
  float mu = sz * (1.f / N_OUT);
  float var = ssz * (1.f / N_OUT) - mu * mu;
  float rs = rsqrtf(var + EPS_GN);
  float zn = (tid < N_OUT)
                 ? (v - mu) * rs * g2[(size_t)blk * N_OUT + tid] + b2[(size_t)blk * N_OUT + tid]
                 : -3.4e38f;
  float mx = block_max(zn, red);
  float e = (tid < N_OUT) ? expf(zn - mx) : 0.f;
  float es = block_sum(e, red);
  if (tid < N_OUT) atomicAdd(&osm[tid * N_HEADS + h], e / es);

  // handshake: last branch of head h does the gating + final outputs
  __syncthreads();               // drain this block's atomics (vmcnt(0) + barrier)
  __threadfence();               // release
  if (tid == 0) bcast = atomicAdd(&cnt[h], 1);
  __syncthreads();
  if (bcast == 3) {
    __threadfence();             // acquire
    float part = 0.f, o_sm = 0.f, sc = 0.f;
    if (tid < N_OUT) {
      // last_prod[o=tid]: 64 contiguous floats (L2-hot, redundant per head)
      const float4* row = (const float4*)(last + (size_t)tid * N_HEADS);
      float lp = 1.f;
#pragma unroll
      for (int j = 0; j < 16; ++j) {
        float4 u = row[j];
        lp *= u.x * u.y * u.z * u.w;
      }
      o_sm = atomicAdd(&osm[tid * N_HEADS + h], 0.f);   // coherent read
      sc   = atomicAdd(&scal[tid * N_HEADS + h], 0.f);  // coherent read
      part = woo[h * 2 * N_OUT + tid] * lp +
             woo[h * 2 * N_OUT + N_OUT + tid] * o_sm;
    }
    float logit = block_sum(part, red);
    float oo = 1.f / (1.f + expf(-logit));
    if (tid < N_OUT) {
      float v0 = oo * o_sm;
      out[tid * N_HEADS + h] = fmaxf(v0, TINY);
      float vv = v0 * sc;
      out[N_OUT * N_HEADS + tid * N_HEADS + h] = (fabsf(vv) <= TINY) ? TINY : vv;
    }
  }
}

extern "C" void kernel_launch(void* const* d_in, const int* in_sizes, int n_in,
                              void* d_out, int out_size, void* d_ws, size_t ws_size,
                              hipStream_t stream) {
  const float* x    = (const float*)d_in[0];
  const float* last = (const float*)d_in[1];
  const float* qw   = (const float*)d_in[2];
  const float* w1   = (const float*)d_in[3];
  const float* g1   = (const float*)d_in[4];
  const float* b1   = (const float*)d_in[5];
  const float* w2   = (const float*)d_in[6];
  const float* g2   = (const float*)d_in[7];
  const float* b2   = (const float*)d_in[8];
  const float* wsc  = (const float*)d_in[9];
  const float* woo  = (const float*)d_in[10];
  float* out = (float*)d_out;
  float* ws  = (float*)d_ws;

  float* z1   = ws;            // 64*512 floats
  float* osm  = ws + 32768;    // 256*64
  float* scal = ws + 49152;    // 256*64
  int*   cnt  = (int*)(ws + 65536);  // 64 ints

  hipLaunchKernelGGL(k_z1,   dim3(256), dim3(512),  0, stream, x, qw, w1, z1, osm, cnt);
  hipLaunchKernelGGL(k_main, dim3(256), dim3(1024), 0, stream,
                     z1, g1, b1, w2, g2, b2, wsc, last, woo, osm, scal, cnt, out);
}

// Round 5
// 261.831 us; speedup vs baseline: 1.2557x; 1.2557x over previous
//
#include <hip/hip_runtime.h>
#include <math.h>

#define N_INP 128
#define N_HID 512
#define N_OUT 256
#define N_HEADS 64
#define N_SM 4
#define EPS_GN 1e-5f
#define TINY 1e-14f

__device__ __forceinline__ float wave_sum(float v) {
#pragma unroll
  for (int off = 32; off; off >>= 1) v += __shfl_down(v, off);
  return v;
}
__device__ __forceinline__ float wave_max(float v) {
#pragma unroll
  for (int off = 32; off; off >>= 1) v = fmaxf(v, __shfl_down(v, off));
  return v;
}

// Block reductions: ALL threads must call; `red` needs blockDim/64 slots.
__device__ __forceinline__ float block_sum(float v, float* red) {
  int wave = threadIdx.x >> 6, lane = threadIdx.x & 63;
  int nw = blockDim.x >> 6;
  v = wave_sum(v);
  __syncthreads();
  if (lane == 0) red[wave] = v;
  __syncthreads();
  float s = 0.f;
  for (int i = 0; i < nw; ++i) s += red[i];
  return s;
}
__device__ __forceinline__ float block_max(float v, float* red) {
  int wave = threadIdx.x >> 6, lane = threadIdx.x & 63;
  int nw = blockDim.x >> 6;
  v = wave_max(v);
  __syncthreads();
  if (lane == 0) red[wave] = v;
  __syncthreads();
  float s = -3.4e38f;
  for (int i = 0; i < nw; ++i) s = fmaxf(s, red[i]);
  return s;
}
// Combined sum of (a, b) in one barrier round — halves GN barrier cost.
__device__ __forceinline__ float2 block_sum2(float a, float b, float2* red2) {
  int wave = threadIdx.x >> 6, lane = threadIdx.x & 63;
  int nw = blockDim.x >> 6;
#pragma unroll
  for (int off = 32; off; off >>= 1) {
    a += __shfl_down(a, off);
    b += __shfl_down(b, off);
  }
  __syncthreads();
  if (lane == 0) red2[wave] = make_float2(a, b);
  __syncthreads();
  float2 s = make_float2(0.f, 0.f);
  for (int i = 0; i < nw; ++i) { s.x += red2[i].x; s.y += red2[i].y; }
  return s;
}

// K1: 256 blocks = (head h, quarter oq). Redundant sub compute (x L2-hot),
// 128 raw z1 rows per block. Also zeroes osm.
__global__ __launch_bounds__(512) void k_z1(
    const float* __restrict__ x, const float* __restrict__ qw,
    const float* __restrict__ w1, float* __restrict__ z1,
    float* __restrict__ osm) {
  int blk = blockIdx.x;            // h*4 + oq
  int h = blk >> 2, oq = blk & 3;
  int tid = threadIdx.x, wave = tid >> 6, lane = tid & 63;
  __shared__ float sub_s[N_INP];

  if (tid < 64) osm[blk * 64 + tid] = 0.f;

  // sub[r] = x[r]·qw[h]; 8 waves × 16 rows
  float2 qv = ((const float2*)(qw + h * N_INP))[lane];
  for (int r = wave; r < N_INP; r += 8) {
    float2 xv = ((const float2*)(x + r * N_INP))[lane];
    float p = wave_sum(xv.x * qv.x + xv.y * qv.y);
    if (lane == 0) sub_s[r] = p;
  }
  __syncthreads();

  // z1 rows [oq*128, oq*128+128): 8 waves × 16 rows
  float2 sv = ((const float2*)sub_s)[lane];
  const float* w1h = w1 + ((size_t)h * N_HID + (size_t)oq * 128) * N_INP;
  for (int k = 0; k < 16; ++k) {
    int o = wave * 16 + k;  // 0..127
    float2 wv = ((const float2*)(w1h + (size_t)o * N_INP))[lane];
    float p = wave_sum(wv.x * sv.x + wv.y * sv.y);
    if (lane == 0) z1[h * N_HID + oq * 128 + o] = p;
  }
}

// K2: 256 blocks = one per (s,h). GN1+softplus from z1 (redundant x4 per head),
// software-pipelined 512KB w2 stream + GN2 + softmax + atomic accumulate, plus
// this block's 64 ws rows fused in. No fences — stream order only.
__global__ __launch_bounds__(1024) void k_l2_scalar(
    const float* __restrict__ z1, const float* __restrict__ g1,
    const float* __restrict__ b1, const float* __restrict__ w2,
    const float* __restrict__ g2, const float* __restrict__ b2,
    const float* __restrict__ wsc, float* __restrict__ osm,
    float* __restrict__ scal) {
  int blk = blockIdx.x;            // s*64 + h
  int s = blk >> 6, h = blk & 63;
  int tid = threadIdx.x, wave = tid >> 6, lane = tid & 63;
  __shared__ float h1_s[N_HID];
  __shared__ float z_s[N_OUT];
  __shared__ float2 red2[16];
  __shared__ float red[16];

  // Prefetch w2 k=0 loads: independent of the GN1 phase — in flight across it.
  const float* w2base = w2 + (size_t)blk * N_OUT * N_HID;
  const float4* row0 = (const float4*)(w2base + (size_t)(wave * 16) * N_HID);
  float4 wa = row0[lane];
  float4 wb = row0[64 + lane];

  // GN1 over 512 + softplus -> h1_s (LDS); combined sum+sumsq (2 barriers)
  float v1 = (tid < N_HID) ? z1[h * N_HID + tid] : 0.f;
  float2 s1 = block_sum2(v1, v1 * v1, red2);
  float mu1 = s1.x * (1.f / N_HID);
  float var1 = s1.y * (1.f / N_HID) - mu1 * mu1;
  float r1 = rsqrtf(var1 + EPS_GN);
  if (tid < N_HID) {
    float zz = (v1 - mu1) * r1 * g1[h * N_HID + tid] + b1[h * N_HID + tid];
    h1_s[tid] = fmaxf(zz, 0.f) + log1pf(expf(-fabsf(zz)));
  }
  __syncthreads();

  // per-lane o-invariant h1 fragment in registers
  float4 ha = ((const float4*)h1_s)[lane];        // i = 4l..4l+3
  float4 hb = ((const float4*)h1_s)[64 + lane];   // i = 256+4l..

  // fused ws slice: rows o in [s*64, (s+1)*64), plain stores (stream order)
  for (int k = 0; k < 4; ++k) {
    int o = s * 64 + wave * 4 + k;
    float4 v = ((const float4*)(wsc + ((size_t)(h * N_OUT + o)) * N_OUT))[lane];
    float p = wave_sum(v.x + v.y + v.z + v.w);
    if (lane == 0) scal[o * N_HEADS + h] = p;
  }

  // main stream, software-pipelined: issue k+1 loads before reducing k
  for (int k = 0; k < 16; ++k) {
    float4 na, nb;
    if (k < 15) {
      const float4* row = (const float4*)(w2base + (size_t)(wave * 16 + k + 1) * N_HID);
      na = row[lane];
      nb = row[64 + lane];
    }
    float p = wa.x * ha.x + wa.y * ha.y + wa.z * ha.z + wa.w * ha.w +
              wb.x * hb.x + wb.y * hb.y + wb.z * hb.z + wb.w * hb.w;
    p = wave_sum(p);
    if (lane == 0) z_s[wave * 16 + k] = p;
    wa = na; wb = nb;
  }
  __syncthreads();

  // GN2 over 256 + softmax + atomic accumulate over s (3 barrier rounds)
  float v = (tid < N_OUT) ? z_s[tid] : 0.f;
  float2 sz = block_sum2(v, v * v, red2);
  float mu = sz.x * (1.f / N_OUT);
  float var = sz.y * (1.f / N_OUT) - mu * mu;
  float rs = rsqrtf(var + EPS_GN);
  float zn = (tid < N_OUT)
                 ? (v - mu) * rs * g2[(size_t)blk * N_OUT + tid] + b2[(size_t)blk * N_OUT + tid]
                 : -3.4e38f;
  float mx = block_max(zn, red);
  float e = (tid < N_OUT) ? expf(zn - mx) : 0.f;
  float es = block_sum(e, red);
  if (tid < N_OUT) atomicAdd(&osm[tid * N_HEADS + h], e / es);
}

// K3: one block per head. last_prod (redundant per block, L2-resident),
// gate logit + sigmoid, final elementwise outputs.
__global__ __launch_bounds__(256) void k_gate_final(
    const float* __restrict__ last, const float* __restrict__ woo,
    const float* __restrict__ osm, const float* __restrict__ scal,
    float* __restrict__ out) {
  int h = blockIdx.x;
  int tid = threadIdx.x;
  __shared__ float red[4];

  // lp[o=tid] = prod_h last[o][h]  (64 contiguous floats per thread)
  const float4* row = (const float4*)(last + (size_t)tid * N_HEADS);
  float p = 1.f;
#pragma unroll
  for (int j = 0; j < 16; ++j) {
    float4 v = row[j];
    p *= v.x * v.y * v.z * v.w;
  }
  float o_sm = osm[tid * N_HEADS + h];
  float part = woo[h * 2 * N_OUT + tid] * p +
               woo[h * 2 * N_OUT + N_OUT + tid] * o_sm;
  float logit = block_sum(part, red);
  float oo = 1.f / (1.f + expf(-logit));

  float v0 = oo * o_sm;
  out[tid * N_HEADS + h] = fmaxf(v0, TINY);
  float v1 = v0 * scal[tid * N_HEADS + h];
  out[N_OUT * N_HEADS + tid * N_HEADS + h] = (fabsf(v1) <= TINY) ? TINY : v1;
}

extern "C" void kernel_launch(void* const* d_in, const int* in_sizes, int n_in,
                              void* d_out, int out_size, void* d_ws, size_t ws_size,
                              hipStream_t stream) {
  const float* x    = (const float*)d_in[0];
  const float* last = (const float*)d_in[1];
  const float* qw   = (const float*)d_in[2];
  const float* w1   = (const float*)d_in[3];
  const float* g1   = (const float*)d_in[4];
  const float* b1   = (const float*)d_in[5];
  const float* w2   = (const float*)d_in[6];
  const float* g2   = (const float*)d_in[7];
  const float* b2   = (const float*)d_in[8];
  const float* wsc  = (const float*)d_in[9];
  const float* woo  = (const float*)d_in[10];
  float* out = (float*)d_out;
  float* ws  = (float*)d_ws;

  float* z1   = ws;           // 64*512
  float* osm  = ws + 32768;   // 256*64
  float* scal = ws + 49152;   // 256*64

  hipLaunchKernelGGL(k_z1,        dim3(256), dim3(512),  0, stream, x, qw, w1, z1, osm);
  hipLaunchKernelGGL(k_l2_scalar, dim3(256), dim3(1024), 0, stream, z1, g1, b1, w2, g2, b2, wsc, osm, scal);
  hipLaunchKernelGGL(k_gate_final,dim3(64),  dim3(256),  0, stream, last, woo, osm, scal, out);
}